// Round 6
// baseline (699.106 us; speedup 1.0000x reference)
//
#include <hip/hip_runtime.h>
#include <hip/hip_bf16.h>

// Problem constants (reference: DIM=1024, 16 heads, hd=64, N=4096, B=1)
#define SEQ     4096
#define NHEADS  16
#define HDIM    64
#define DIMSZ   1024
#define ATT_SCALE 0.125f   // 64^-0.5

static constexpr size_t QSZ = (size_t)NHEADS * SEQ * HDIM;   // 4194304 elems

typedef __attribute__((ext_vector_type(8))) short short8;
typedef __attribute__((ext_vector_type(4))) short s16x4;
typedef __attribute__((ext_vector_type(8))) unsigned short ushort8;
typedef __attribute__((ext_vector_type(4))) float f32x4;
#define MFMA_BF16(a, b, c) __builtin_amdgcn_mfma_f32_16x16x32_bf16((a), (b), (c), 0, 0, 0)

__device__ __forceinline__ unsigned short f2bfu(float x) {
    __hip_bfloat16 h = __float2bfloat16(x);   // RNE
    return *reinterpret_cast<unsigned short*>(&h);
}
__device__ __forceinline__ float bfu2f(unsigned short u) {
    __hip_bfloat16 h = *reinterpret_cast<__hip_bfloat16*>(&u);
    return __bfloat162float(h);
}
__device__ __forceinline__ void split8(float4 f0, float4 f1, ushort8& h, ushort8& l) {
    const float v[8] = {f0.x, f0.y, f0.z, f0.w, f1.x, f1.y, f1.z, f1.w};
    #pragma unroll
    for (int i = 0; i < 8; ++i) {
        const unsigned short hi = f2bfu(v[i]);
        h[i] = hi;
        l[i] = f2bfu(v[i] - bfu2f(hi));
    }
}

// ---------------------------------------------------------------------------
// split3: elementwise fp32 -> (hi, lo) bf16 planes for up to 3 tensors.
// ---------------------------------------------------------------------------
__global__ void split3(const float* __restrict__ s0, unsigned short* __restrict__ h0,
                       unsigned short* __restrict__ l0, int n0,
                       const float* __restrict__ s1, unsigned short* __restrict__ h1,
                       unsigned short* __restrict__ l1, int n1,
                       const float* __restrict__ s2, unsigned short* __restrict__ h2,
                       unsigned short* __restrict__ l2, int n2)
{
    const int stride = gridDim.x * blockDim.x;
    const int tid = blockIdx.x * blockDim.x + threadIdx.x;
    for (int i = tid; i < (n0 >> 2); i += stride) {
        float4 v = ((const float4*)s0)[i];
        ushort4 h, l;
        h.x = f2bfu(v.x); l.x = f2bfu(v.x - bfu2f(h.x));
        h.y = f2bfu(v.y); l.y = f2bfu(v.y - bfu2f(h.y));
        h.z = f2bfu(v.z); l.z = f2bfu(v.z - bfu2f(h.z));
        h.w = f2bfu(v.w); l.w = f2bfu(v.w - bfu2f(h.w));
        ((ushort4*)h0)[i] = h; ((ushort4*)l0)[i] = l;
    }
    for (int i = tid; i < (n1 >> 2); i += stride) {
        float4 v = ((const float4*)s1)[i];
        ushort4 h, l;
        h.x = f2bfu(v.x); l.x = f2bfu(v.x - bfu2f(h.x));
        h.y = f2bfu(v.y); l.y = f2bfu(v.y - bfu2f(h.y));
        h.z = f2bfu(v.z); l.z = f2bfu(v.z - bfu2f(h.z));
        h.w = f2bfu(v.w); l.w = f2bfu(v.w - bfu2f(h.w));
        ((ushort4*)h1)[i] = h; ((ushort4*)l1)[i] = l;
    }
    if (n2 > 0) {
        for (int i = tid; i < (n2 >> 2); i += stride) {
            float4 v = ((const float4*)s2)[i];
            ushort4 h, l;
            h.x = f2bfu(v.x); l.x = f2bfu(v.x - bfu2f(h.x));
            h.y = f2bfu(v.y); l.y = f2bfu(v.y - bfu2f(h.y));
            h.z = f2bfu(v.z); l.z = f2bfu(v.z - bfu2f(h.z));
            h.w = f2bfu(v.w); l.w = f2bfu(v.w - bfu2f(h.w));
            ((ushort4*)h2)[i] = h; ((ushort4*)l2)[i] = l;
        }
    }
}

// ---------------------------------------------------------------------------
// MFMA GEMM: C = A * B^T (+bias), split-bf16 (3-term: AhBh + AlBh + AhBl).
// 128x128 tile, BK=32, 256 thr = 4 waves. ASPLIT/BSPLIT: operand comes
// pre-split as bf16 hi/lo planes (staging = pure copies, no VALU convert).
// MODE 0: C[M,N] = acc + bias[col]  (fp32 out)
// MODE 1: QKV epilogue -> pre-converted bf16 attention operands.
// ---------------------------------------------------------------------------
#define GPAD 40
template <int MODE, bool ASPLIT, bool BSPLIT>
__global__ __launch_bounds__(256, 3)
void mfma_gemm_abt(const float* __restrict__ A,
                   const unsigned short* __restrict__ AHg,
                   const unsigned short* __restrict__ ALg,
                   const float* __restrict__ B,
                   const unsigned short* __restrict__ BHg,
                   const unsigned short* __restrict__ BLg,
                   const float* __restrict__ bias, float* __restrict__ C,
                   unsigned short* __restrict__ QH, unsigned short* __restrict__ QL,
                   unsigned short* __restrict__ KH, unsigned short* __restrict__ KL,
                   unsigned short* __restrict__ VT, int M, int N, int K)
{
    __shared__ unsigned short AHs[128 * GPAD];
    __shared__ unsigned short ALs[128 * GPAD];
    __shared__ unsigned short BHs[128 * GPAD];
    __shared__ unsigned short BLs[128 * GPAD];

    const int t  = threadIdx.x;
    const int wv = t >> 6;
    const int ln = t & 63;
    const int lx = ln & 15;
    const int q4 = ln >> 4;
    const int m0 = blockIdx.y * 128;
    const int n0 = blockIdx.x * 128;

    f32x4 acc[2][8];
    #pragma unroll
    for (int mf = 0; mf < 2; ++mf)
        #pragma unroll
        for (int nf = 0; nf < 8; ++nf)
            acc[mf][nf] = (f32x4){0.f, 0.f, 0.f, 0.f};

    for (int k0 = 0; k0 < K; k0 += 32) {
        #pragma unroll
        for (int rep = 0; rep < 2; ++rep) {
            const int task = rep * 256 + t;          // 0..511
            const int r  = task >> 2;
            const int sg = (task & 3) << 3;          // element offset 0,8,16,24
            if constexpr (ASPLIT) {
                const size_t off = (size_t)(m0 + r) * K + k0 + sg;
                *(ushort8*)&AHs[r * GPAD + sg] = *(const ushort8*)(AHg + off);
                *(ushort8*)&ALs[r * GPAD + sg] = *(const ushort8*)(ALg + off);
            } else {
                const float* p = A + (size_t)(m0 + r) * K + k0 + sg;
                float4 f0 = *(const float4*)p;
                float4 f1 = *(const float4*)(p + 4);
                ushort8 h, l; split8(f0, f1, h, l);
                *(ushort8*)&AHs[r * GPAD + sg] = h;
                *(ushort8*)&ALs[r * GPAD + sg] = l;
            }
            if constexpr (BSPLIT) {
                const size_t off = (size_t)(n0 + r) * K + k0 + sg;
                *(ushort8*)&BHs[r * GPAD + sg] = *(const ushort8*)(BHg + off);
                *(ushort8*)&BLs[r * GPAD + sg] = *(const ushort8*)(BLg + off);
            } else {
                const float* p = B + (size_t)(n0 + r) * K + k0 + sg;
                float4 f0 = *(const float4*)p;
                float4 f1 = *(const float4*)(p + 4);
                ushort8 h, l; split8(f0, f1, h, l);
                *(ushort8*)&BHs[r * GPAD + sg] = h;
                *(ushort8*)&BLs[r * GPAD + sg] = l;
            }
        }
        __syncthreads();

        short8 ah[2], al[2];
        #pragma unroll
        for (int mf = 0; mf < 2; ++mf) {
            const int row = wv * 32 + mf * 16 + lx;
            ah[mf] = *(const short8*)&AHs[row * GPAD + q4 * 8];
            al[mf] = *(const short8*)&ALs[row * GPAD + q4 * 8];
        }
        #pragma unroll
        for (int nf = 0; nf < 8; ++nf) {
            const int brow = nf * 16 + lx;
            const short8 bh = *(const short8*)&BHs[brow * GPAD + q4 * 8];
            const short8 bl = *(const short8*)&BLs[brow * GPAD + q4 * 8];
            #pragma unroll
            for (int mf = 0; mf < 2; ++mf) {
                acc[mf][nf] = MFMA_BF16(ah[mf], bh, acc[mf][nf]);
                acc[mf][nf] = MFMA_BF16(al[mf], bh, acc[mf][nf]);
                acc[mf][nf] = MFMA_BF16(ah[mf], bl, acc[mf][nf]);
            }
        }
        __syncthreads();
    }

    // ---- epilogue (C-frag: row = q4*4+r, col = lx within each 16x16) ----
    if constexpr (MODE == 0) {
        #pragma unroll
        for (int nf = 0; nf < 8; ++nf) {
            const int col = n0 + nf * 16 + lx;
            const float bv = bias[col];
            #pragma unroll
            for (int mf = 0; mf < 2; ++mf) {
                const int row0 = m0 + wv * 32 + mf * 16 + q4 * 4;
                #pragma unroll
                for (int r = 0; r < 4; ++r)
                    C[(size_t)(row0 + r) * N + col] = acc[mf][nf][r] + bv;
            }
        }
    } else {
        const int part = n0 >> 10;                   // whole block in one part
        #pragma unroll
        for (int nf = 0; nf < 8; ++nf) {
            const int colb = n0 + nf * 16;
            const int head = (colb >> 6) & 15;
            const int d0   = (colb & 63) + lx;
            if (part == 0) {
                #pragma unroll
                for (int mf = 0; mf < 2; ++mf) {
                    const int row0 = m0 + wv * 32 + mf * 16 + q4 * 4;
                    #pragma unroll
                    for (int r = 0; r < 4; ++r) {
                        const float v = acc[mf][nf][r] * ATT_SCALE;
                        const unsigned short h = f2bfu(v);
                        const size_t idx = ((size_t)head * SEQ + row0 + r) * HDIM + d0;
                        QH[idx] = h;
                        QL[idx] = f2bfu(v - bfu2f(h));
                    }
                }
            } else if (part == 1) {
                #pragma unroll
                for (int mf = 0; mf < 2; ++mf) {
                    const int row0 = m0 + wv * 32 + mf * 16 + q4 * 4;
                    #pragma unroll
                    for (int r = 0; r < 4; ++r) {
                        const float v = acc[mf][nf][r];
                        const unsigned short h = f2bfu(v);
                        const size_t idx = ((size_t)head * SEQ + row0 + r) * HDIM + d0;
                        KH[idx] = h;
                        KL[idx] = f2bfu(v - bfu2f(h));
                    }
                }
            } else {
                // V bf16 transposed: VT[head][d0][n], 4 consecutive n -> ushort4
                unsigned short* base = VT + ((size_t)head * HDIM + d0) * SEQ;
                #pragma unroll
                for (int mf = 0; mf < 2; ++mf) {
                    const int row0 = m0 + wv * 32 + mf * 16 + q4 * 4;
                    ushort4 o;
                    o.x = f2bfu(acc[mf][nf][0]); o.y = f2bfu(acc[mf][nf][1]);
                    o.z = f2bfu(acc[mf][nf][2]); o.w = f2bfu(acc[mf][nf][3]);
                    *(ushort4*)(base + row0) = o;
                }
            }
        }
    }
}

// ---------------------------------------------------------------------------
// Flash attention, MFMA, S^T formulation, register-resident P transit.
// Wave w owns keys [w*16, w*16+16) of each 64-key sub-tile; mega-tile = 128
// keys (2 sub-tiles) so the PV MFMA gets a full K=32 from two quad-key runs.
// S^T = K·Q^T: A=K (hi/lo from LDS), B=Q (hi/lo frags in registers, loaded
// once). exp(S^T) in C-layout == PV B-operand layout (k=quad*8+j mapped to
// [sub0: quad*4+j | sub1: quad*4+(j-4)]), V^T A-frags read with the same
// permutation (two ds_read_b64). Static-max softmax (R5-validated). Per-wave
// key-partial O^T + l reduced through LDS once at the end; output written
// pre-split (hi/lo bf16) for the projection GEMM.
// LDS: KHI[128][68], KLO[128][68], VS[64][136] ushort = 52224 B.
// ---------------------------------------------------------------------------
__global__ __launch_bounds__(256, 2)
void attn_mfma(const unsigned short* __restrict__ QHg,
               const unsigned short* __restrict__ QLg,
               const unsigned short* __restrict__ KHg,
               const unsigned short* __restrict__ KLg,
               const unsigned short* __restrict__ VTg,
               unsigned short* __restrict__ AttnH,
               unsigned short* __restrict__ AttnL)
{
    __shared__ __align__(16) char shraw[52224];
    unsigned short* KHI = (unsigned short*)shraw;              // [128][68]
    unsigned short* KLO = (unsigned short*)(shraw + 17408);    // [128][68]
    unsigned short* VS  = (unsigned short*)(shraw + 34816);    // [64][136]
    float* obuf = (float*)shraw;                               // [4][32][68]
    float* lbuf = (float*)(shraw + 34816);                     // [4][64]

    const int t  = threadIdx.x;
    const int wv = t >> 6;
    const int ln = t & 63;
    const int q4 = ln >> 4;
    const int lx = ln & 15;
    const int qb   = blockIdx.x;
    const int head = blockIdx.y;

    const unsigned short* Kh = KHg + (size_t)head * SEQ * HDIM;   // [n][64]
    const unsigned short* Kl = KLg + (size_t)head * SEQ * HDIM;
    const unsigned short* Vg = VTg + (size_t)head * HDIM * SEQ;   // [d][4096]

    // ---- Q B-frags, held in registers for the whole kernel ----
    short8 qh[4][2], ql[4][2];
    #pragma unroll
    for (int qt = 0; qt < 4; ++qt)
        #pragma unroll
        for (int s = 0; s < 2; ++s) {
            const size_t off = ((size_t)head * SEQ + (size_t)qb * 64 + qt * 16 + lx) * HDIM
                             + s * 32 + q4 * 8;
            qh[qt][s] = *(const short8*)(QHg + off);
            ql[qt][s] = *(const short8*)(QLg + off);
        }

    f32x4 o_acc[4][4];   // [dt][qt]: O^T[d=dt*16+q4*4+r][q=qt*16+lx] (wave-partial)
    float l_part[4] = {0.f, 0.f, 0.f, 0.f};
    #pragma unroll
    for (int dt = 0; dt < 4; ++dt)
        #pragma unroll
        for (int qt = 0; qt < 4; ++qt)
            o_acc[dt][qt] = (f32x4){0.f, 0.f, 0.f, 0.f};

    for (int mt = 0; mt < SEQ / 128; ++mt) {
        const int kbase = mt * 128;
        // ---- stage K hi/lo [128 keys][64 d] and V^T [64 d][128 keys] ----
        ushort8 bk[4], bl[4], bv[4];
        #pragma unroll
        for (int it = 0; it < 4; ++it) {
            const int idx = it * 256 + t;            // 0..1023
            const int r  = idx >> 3, c8 = (idx & 7) << 3;
            bk[it] = *(const ushort8*)(Kh + (size_t)(kbase + r) * HDIM + c8);
            bl[it] = *(const ushort8*)(Kl + (size_t)(kbase + r) * HDIM + c8);
            const int rv = idx >> 4, cv = (idx & 15) << 3;
            bv[it] = *(const ushort8*)(Vg + (size_t)rv * SEQ + kbase + cv);
        }
        #pragma unroll
        for (int it = 0; it < 4; ++it) {
            const int idx = it * 256 + t;
            const int r  = idx >> 3, c8 = (idx & 7) << 3;
            *(ushort8*)&KHI[r * 68 + c8] = bk[it];
            *(ushort8*)&KLO[r * 68 + c8] = bl[it];
            const int rv = idx >> 4, cv = (idx & 15) << 3;
            *(ushort8*)&VS[rv * 136 + cv] = bv[it];
        }
        __syncthreads();

        // ---- S^T = K Q^T per sub-tile; exp packs straight into PV B-frags ----
        short8 phi[4], plo[4];
        #pragma unroll
        for (int st = 0; st < 2; ++st) {
            const int kr = st * 64 + wv * 16 + lx;   // this lane's A-row (key)
            short8 kfh[2], kfl[2];
            #pragma unroll
            for (int s = 0; s < 2; ++s) {
                kfh[s] = *(const short8*)&KHI[kr * 68 + s * 32 + q4 * 8];
                kfl[s] = *(const short8*)&KLO[kr * 68 + s * 32 + q4 * 8];
            }
            #pragma unroll
            for (int qt = 0; qt < 4; ++qt) {
                f32x4 sa = (f32x4){0.f, 0.f, 0.f, 0.f};
                #pragma unroll
                for (int s = 0; s < 2; ++s) {
                    sa = MFMA_BF16(kfh[s], qh[qt][s], sa);
                    sa = MFMA_BF16(kfl[s], qh[qt][s], sa);
                    sa = MFMA_BF16(kfh[s], ql[qt][s], sa);
                }
                #pragma unroll
                for (int r = 0; r < 4; ++r) {
                    const float e = __expf(sa[r]);
                    l_part[qt] += e;
                    const unsigned short h = f2bfu(e);
                    phi[qt][st * 4 + r] = (short)h;
                    plo[qt][st * 4 + r] = (short)f2bfu(e - bfu2f(h));
                }
            }
        }

        // ---- O^T += V^T P^T  (A=V^T two b64 reads w/ matching permutation) ----
        #pragma unroll
        for (int dt = 0; dt < 4; ++dt) {
            const int vrow = (dt * 16 + lx) * 136 + wv * 16 + q4 * 4;
            const s16x4 v0 = *(const s16x4*)&VS[vrow];
            const s16x4 v1 = *(const s16x4*)&VS[vrow + 64];
            short8 vf;
            #pragma unroll
            for (int i = 0; i < 4; ++i) { vf[i] = v0[i]; vf[i + 4] = v1[i]; }
            #pragma unroll
            for (int qt = 0; qt < 4; ++qt) {
                o_acc[dt][qt] = MFMA_BF16(vf, phi[qt], o_acc[dt][qt]);
                o_acc[dt][qt] = MFMA_BF16(vf, plo[qt], o_acc[dt][qt]);
            }
        }
        __syncthreads();   // staging buffers reused next mega-tile
    }

    // ---- epilogue: reduce l and O^T across the 4 waves, write split out ----
    float lw[4];
    #pragma unroll
    for (int qt = 0; qt < 4; ++qt) {
        float l = l_part[qt];
        l += __shfl_xor(l, 16);
        l += __shfl_xor(l, 32);
        lw[qt] = l;                                  // wave-total for q=qt*16+lx
    }
    // (main loop's trailing barrier protects VS/KHI reuse below)
    if (q4 == 0) {
        #pragma unroll
        for (int qt = 0; qt < 4; ++qt)
            lbuf[wv * 64 + qt * 16 + lx] = lw[qt];
    }
    #pragma unroll
    for (int p = 0; p < 2; ++p) {
        #pragma unroll
        for (int dd = 0; dd < 2; ++dd) {
            const int dt = p * 2 + dd;
            #pragma unroll
            for (int qt = 0; qt < 4; ++qt)
                #pragma unroll
                for (int r = 0; r < 4; ++r)
                    obuf[wv * 2176 + (dd * 16 + q4 * 4 + r) * 68 + qt * 16 + lx]
                        = o_acc[dt][qt][r];
        }
        __syncthreads();
        {
            const int q  = t >> 2;
            const int dg = (t & 3) << 3;
            const float linv = 1.f / (lbuf[q] + lbuf[64 + q] + lbuf[128 + q] + lbuf[192 + q]);
            ushort8 ho, lo;
            #pragma unroll
            for (int j = 0; j < 8; ++j) {
                const int dloc = dg + j;
                const float s = obuf[dloc * 68 + q] + obuf[2176 + dloc * 68 + q]
                              + obuf[4352 + dloc * 68 + q] + obuf[6528 + dloc * 68 + q];
                const float v = s * linv;
                const unsigned short h = f2bfu(v);
                ho[j] = (short)h;
                lo[j] = (short)f2bfu(v - bfu2f(h));
            }
            const size_t ob = (size_t)(qb * 64 + q) * DIMSZ + head * HDIM + p * 32 + dg;
            *(ushort8*)(AttnH + ob) = ho;
            *(ushort8*)(AttnL + ob) = lo;
        }
        __syncthreads();
    }
}

// ---------------------------------------------------------------------------
extern "C" void kernel_launch(void* const* d_in, const int* in_sizes, int n_in,
                              void* d_out, int out_size, void* d_ws,
                              size_t ws_size, hipStream_t stream)
{
    const float* x     = (const float*)d_in[0];   // [4096, 3072]
    const float* Wqkv  = (const float*)d_in[1];   // [3072, 3072]
    const float* Wproj = (const float*)d_in[2];   // [1024, 1024]
    const float* bproj = (const float*)d_in[3];   // [1024]
    float* out = (float*)d_out;

    unsigned short* ub = (unsigned short*)d_ws;
    unsigned short* AttnH = ub;                   // [4096][1024]
    unsigned short* AttnL = ub + QSZ;
    unsigned short* QHg = ub + 2 * QSZ;           // [16][4096][64]
    unsigned short* QLg = ub + 3 * QSZ;
    unsigned short* KHg = ub + 4 * QSZ;
    unsigned short* KLg = ub + 5 * QSZ;
    unsigned short* VTg = ub + 6 * QSZ;           // [16][64][4096]
    // optional pre-split planes (runtime-gated on ws_size; constant per session)
    const size_t NWQ = 3072 * 3072, NWP = 1024 * 1024, NX = (size_t)4096 * 3072;
    unsigned short* WQH = ub + 7 * QSZ;
    unsigned short* WQL = WQH + NWQ;
    unsigned short* WPH = WQL + NWQ;
    unsigned short* WPL = WPH + NWP;
    unsigned short* XH  = WPL + NWP;
    unsigned short* XL  = XH + NX;
    const bool wsplit = ws_size >= 100663296ull;  // base 58.7MB + W planes 41.9MB
    const bool xsplit = ws_size >= 150994944ull;  // + x planes 50.3MB

    if (wsplit) {
        split3<<<2048, 256, 0, stream>>>(
            Wqkv, WQH, WQL, (int)NWQ,
            Wproj, WPH, WPL, (int)NWP,
            xsplit ? x : nullptr, XH, XL, xsplit ? (int)NX : 0);
    }

    // 1) qkv = x @ Wqkv^T -> pre-converted attention operands
    dim3 g1(3 * DIMSZ / 128, SEQ / 128);   // 24 x 32
    if (xsplit)
        mfma_gemm_abt<1, true, true><<<g1, 256, 0, stream>>>(
            nullptr, XH, XL, nullptr, WQH, WQL, nullptr, nullptr,
            QHg, QLg, KHg, KLg, VTg, SEQ, 3 * DIMSZ, 3 * DIMSZ);
    else if (wsplit)
        mfma_gemm_abt<1, false, true><<<g1, 256, 0, stream>>>(
            x, nullptr, nullptr, nullptr, WQH, WQL, nullptr, nullptr,
            QHg, QLg, KHg, KLg, VTg, SEQ, 3 * DIMSZ, 3 * DIMSZ);
    else
        mfma_gemm_abt<1, false, false><<<g1, 256, 0, stream>>>(
            x, nullptr, nullptr, Wqkv, nullptr, nullptr, nullptr, nullptr,
            QHg, QLg, KHg, KLg, VTg, SEQ, 3 * DIMSZ, 3 * DIMSZ);

    // 2) attention (S^T keys-per-wave, register P transit), split output
    dim3 g2(SEQ / 64, NHEADS);             // 64 x 16
    attn_mfma<<<g2, 256, 0, stream>>>(QHg, QLg, KHg, KLg, VTg, AttnH, AttnL);

    // 3) out = attn @ Wproj^T + bproj
    dim3 g3(DIMSZ / 128, SEQ / 128);       // 8 x 32
    if (wsplit)
        mfma_gemm_abt<0, true, true><<<g3, 256, 0, stream>>>(
            nullptr, AttnH, AttnL, nullptr, WPH, WPL, bproj, out,
            nullptr, nullptr, nullptr, nullptr, nullptr, SEQ, DIMSZ, DIMSZ);
    else
        mfma_gemm_abt<0, true, false><<<g3, 256, 0, stream>>>(
            nullptr, AttnH, AttnL, Wproj, nullptr, nullptr, bproj, out,
            nullptr, nullptr, nullptr, nullptr, nullptr, SEQ, DIMSZ, DIMSZ);
}

// Round 7
// 542.320 us; speedup vs baseline: 1.2891x; 1.2891x over previous
//
#include <hip/hip_runtime.h>
#include <hip/hip_fp16.h>

// Problem constants (reference: DIM=1024, 16 heads, hd=64, N=4096, B=1)
#define SEQ     4096
#define NHEADS  16
#define HDIM    64
#define DIMSZ   1024
#define ATT_SCALE 0.125f   // 64^-0.5

static constexpr size_t QSZ = (size_t)NHEADS * SEQ * HDIM;   // 4194304 elems

typedef __attribute__((ext_vector_type(8))) short short8;
typedef __attribute__((ext_vector_type(4))) short s16x4;
typedef __attribute__((ext_vector_type(8))) unsigned short ushort8;
typedef __attribute__((ext_vector_type(4))) float f32x4;
#define MFMA_F16(a, b, c) __builtin_amdgcn_mfma_f32_16x16x32_f16((a), (b), (c), 0, 0, 0)

__device__ __forceinline__ unsigned short f2hu(float x) {
    __half h = __float2half(x);   // RNE
    return *reinterpret_cast<unsigned short*>(&h);
}
__device__ __forceinline__ float hu2f(unsigned short u) {
    __half h = *reinterpret_cast<__half*>(&u);
    return __half2float(h);
}
__device__ __forceinline__ void split8h(float4 f0, float4 f1, ushort8& h, ushort8& l) {
    const float v[8] = {f0.x, f0.y, f0.z, f0.w, f1.x, f1.y, f1.z, f1.w};
    #pragma unroll
    for (int i = 0; i < 8; ++i) {
        const unsigned short hi = f2hu(v[i]);
        h[i] = hi;
        l[i] = f2hu(v[i] - hu2f(hi));
    }
}
__device__ __forceinline__ ushort8 cast8h(float4 f0, float4 f1) {
    const float v[8] = {f0.x, f0.y, f0.z, f0.w, f1.x, f1.y, f1.z, f1.w};
    ushort8 h;
    #pragma unroll
    for (int i = 0; i < 8; ++i) h[i] = f2hu(v[i]);
    return h;
}

// ---------------------------------------------------------------------------
// prep_split: x -> fp16 hi+lo planes (optional); W_qkv, W_proj -> fp16 hi only.
// ---------------------------------------------------------------------------
__global__ void prep_split(const float* __restrict__ x, unsigned short* __restrict__ xh,
                           unsigned short* __restrict__ xl, int nx,
                           const float* __restrict__ w0, unsigned short* __restrict__ w0h,
                           int n0,
                           const float* __restrict__ w1, unsigned short* __restrict__ w1h,
                           int n1)
{
    const int stride = gridDim.x * blockDim.x;
    const int tid = blockIdx.x * blockDim.x + threadIdx.x;
    for (int i = tid; i < (nx >> 2); i += stride) {
        float4 v = ((const float4*)x)[i];
        ushort4 h, l;
        h.x = f2hu(v.x); l.x = f2hu(v.x - hu2f(h.x));
        h.y = f2hu(v.y); l.y = f2hu(v.y - hu2f(h.y));
        h.z = f2hu(v.z); l.z = f2hu(v.z - hu2f(h.z));
        h.w = f2hu(v.w); l.w = f2hu(v.w - hu2f(h.w));
        ((ushort4*)xh)[i] = h; ((ushort4*)xl)[i] = l;
    }
    for (int i = tid; i < (n0 >> 2); i += stride) {
        float4 v = ((const float4*)w0)[i];
        ushort4 h;
        h.x = f2hu(v.x); h.y = f2hu(v.y); h.z = f2hu(v.z); h.w = f2hu(v.w);
        ((ushort4*)w0h)[i] = h;
    }
    for (int i = tid; i < (n1 >> 2); i += stride) {
        float4 v = ((const float4*)w1)[i];
        ushort4 h;
        h.x = f2hu(v.x); h.y = f2hu(v.y); h.z = f2hu(v.z); h.w = f2hu(v.w);
        ((ushort4*)w1h)[i] = h;
    }
}

// ---------------------------------------------------------------------------
// MFMA GEMM: C = A * B^T (+bias), fp16 2-term: Ah*Bh + Al*Bh (B single fp16).
// A[M,K], B[N,K] logical row-major. 128x128 tile, BK=32, 256 thr = 4 waves.
// ASPLIT: A comes pre-split (AHg/ALg fp16 planes); else split in staging.
// MODE 0: C[M,N] = acc + bias[col]  (fp32 out)
// MODE 1: QKV epilogue: part 0 Q -> hi/lo*SCALE [h][n][64]; part 1 K -> hi
//         only [h][n][64]; part 2 V -> fp16 transposed [h][d][4096].
// ---------------------------------------------------------------------------
#define GPAD 40
template <int MODE, bool ASPLIT>
__global__ __launch_bounds__(256, 3)
void mfma_gemm_abt(const float* __restrict__ A,
                   const unsigned short* __restrict__ AHg,
                   const unsigned short* __restrict__ ALg,
                   const unsigned short* __restrict__ BHg,
                   const float* __restrict__ bias, float* __restrict__ C,
                   unsigned short* __restrict__ QH, unsigned short* __restrict__ QL,
                   unsigned short* __restrict__ KH, unsigned short* __restrict__ VT,
                   int M, int N, int K)
{
    __shared__ unsigned short AHs[128 * GPAD];
    __shared__ unsigned short ALs[128 * GPAD];
    __shared__ unsigned short BHs[128 * GPAD];

    const int t  = threadIdx.x;
    const int wv = t >> 6;
    const int ln = t & 63;
    const int lx = ln & 15;
    const int q4 = ln >> 4;
    const int m0 = blockIdx.y * 128;
    const int n0 = blockIdx.x * 128;

    f32x4 acc[2][8];
    #pragma unroll
    for (int mf = 0; mf < 2; ++mf)
        #pragma unroll
        for (int nf = 0; nf < 8; ++nf)
            acc[mf][nf] = (f32x4){0.f, 0.f, 0.f, 0.f};

    for (int k0 = 0; k0 < K; k0 += 32) {
        #pragma unroll
        for (int rep = 0; rep < 2; ++rep) {
            const int task = rep * 256 + t;          // 0..511
            const int r  = task >> 2;
            const int sg = (task & 3) << 3;          // element offset 0,8,16,24
            if constexpr (ASPLIT) {
                const size_t off = (size_t)(m0 + r) * K + k0 + sg;
                *(ushort8*)&AHs[r * GPAD + sg] = *(const ushort8*)(AHg + off);
                *(ushort8*)&ALs[r * GPAD + sg] = *(const ushort8*)(ALg + off);
            } else {
                const float* p = A + (size_t)(m0 + r) * K + k0 + sg;
                float4 f0 = *(const float4*)p;
                float4 f1 = *(const float4*)(p + 4);
                ushort8 h, l; split8h(f0, f1, h, l);
                *(ushort8*)&AHs[r * GPAD + sg] = h;
                *(ushort8*)&ALs[r * GPAD + sg] = l;
            }
            {
                const size_t off = (size_t)(n0 + r) * K + k0 + sg;
                *(ushort8*)&BHs[r * GPAD + sg] = *(const ushort8*)(BHg + off);
            }
        }
        __syncthreads();

        short8 ah[2], al[2];
        #pragma unroll
        for (int mf = 0; mf < 2; ++mf) {
            const int row = wv * 32 + mf * 16 + lx;
            ah[mf] = *(const short8*)&AHs[row * GPAD + q4 * 8];
            al[mf] = *(const short8*)&ALs[row * GPAD + q4 * 8];
        }
        #pragma unroll
        for (int nf = 0; nf < 8; ++nf) {
            const short8 bh = *(const short8*)&BHs[(nf * 16 + lx) * GPAD + q4 * 8];
            #pragma unroll
            for (int mf = 0; mf < 2; ++mf) {
                acc[mf][nf] = MFMA_F16(ah[mf], bh, acc[mf][nf]);
                acc[mf][nf] = MFMA_F16(al[mf], bh, acc[mf][nf]);
            }
        }
        __syncthreads();
    }

    // ---- epilogue (C-frag: row = q4*4+r, col = lx within each 16x16) ----
    if constexpr (MODE == 0) {
        #pragma unroll
        for (int nf = 0; nf < 8; ++nf) {
            const int col = n0 + nf * 16 + lx;
            const float bv = bias[col];
            #pragma unroll
            for (int mf = 0; mf < 2; ++mf) {
                const int row0 = m0 + wv * 32 + mf * 16 + q4 * 4;
                #pragma unroll
                for (int r = 0; r < 4; ++r)
                    C[(size_t)(row0 + r) * N + col] = acc[mf][nf][r] + bv;
            }
        }
    } else {
        const int part = n0 >> 10;                   // whole block in one part
        #pragma unroll
        for (int nf = 0; nf < 8; ++nf) {
            const int colb = n0 + nf * 16;
            const int head = (colb >> 6) & 15;
            const int d0   = (colb & 63) + lx;
            if (part == 0) {
                #pragma unroll
                for (int mf = 0; mf < 2; ++mf) {
                    const int row0 = m0 + wv * 32 + mf * 16 + q4 * 4;
                    #pragma unroll
                    for (int r = 0; r < 4; ++r) {
                        const float v = acc[mf][nf][r] * ATT_SCALE;
                        const unsigned short h = f2hu(v);
                        const size_t idx = ((size_t)head * SEQ + row0 + r) * HDIM + d0;
                        QH[idx] = h;
                        QL[idx] = f2hu(v - hu2f(h));
                    }
                }
            } else if (part == 1) {
                #pragma unroll
                for (int mf = 0; mf < 2; ++mf) {
                    const int row0 = m0 + wv * 32 + mf * 16 + q4 * 4;
                    #pragma unroll
                    for (int r = 0; r < 4; ++r) {
                        const size_t idx = ((size_t)head * SEQ + row0 + r) * HDIM + d0;
                        KH[idx] = f2hu(acc[mf][nf][r]);
                    }
                }
            } else {
                // V fp16 transposed: VT[head][d0][n], 4 consecutive n -> ushort4
                unsigned short* base = VT + ((size_t)head * HDIM + d0) * SEQ;
                #pragma unroll
                for (int mf = 0; mf < 2; ++mf) {
                    const int row0 = m0 + wv * 32 + mf * 16 + q4 * 4;
                    ushort4 o;
                    o.x = f2hu(acc[mf][nf][0]); o.y = f2hu(acc[mf][nf][1]);
                    o.z = f2hu(acc[mf][nf][2]); o.w = f2hu(acc[mf][nf][3]);
                    *(ushort4*)(base + row0) = o;
                }
            }
        }
    }
}

// ---------------------------------------------------------------------------
// Flash attention, fp16 MFMA, S^T formulation, register-resident P transit.
// S^T = K·Q^T: A=K (hi only, from LDS), B=Q (hi+lo frags in registers).
// PV: 1 term, P single fp16 x V single fp16. Static-max softmax.
// Wave w owns keys [w*16,w*16+16) of each 64-key sub-tile; 128-key mega-tile.
// exp(S^T) C-layout == PV B-operand layout (k=[sub0 quad keys|sub1 quad keys]);
// V^T A-frags read with matching permutation (two ds_read_b64).
// LDS: KHI[128][68] + VS[64][136] ushort = 34816 B; epilogue obuf+lbuf 35840 B.
// ---------------------------------------------------------------------------
__global__ __launch_bounds__(256, 2)
void attn_mfma(const unsigned short* __restrict__ QHg,
               const unsigned short* __restrict__ QLg,
               const unsigned short* __restrict__ KHg,
               const unsigned short* __restrict__ VTg,
               unsigned short* __restrict__ AttnH,
               unsigned short* __restrict__ AttnL)
{
    __shared__ __align__(16) char shraw[35840];
    unsigned short* KHI = (unsigned short*)shraw;              // [128][68]
    unsigned short* VS  = (unsigned short*)(shraw + 17408);    // [64][136]
    float* obuf = (float*)shraw;                               // [4][32][68]
    float* lbuf = (float*)(shraw + 34816);                     // [4][64]

    const int t  = threadIdx.x;
    const int wv = t >> 6;
    const int ln = t & 63;
    const int q4 = ln >> 4;
    const int lx = ln & 15;
    const int qb   = blockIdx.x;
    const int head = blockIdx.y;

    const unsigned short* Kh = KHg + (size_t)head * SEQ * HDIM;   // [n][64]
    const unsigned short* Vg = VTg + (size_t)head * HDIM * SEQ;   // [d][4096]

    // ---- Q B-frags, held in registers for the whole kernel ----
    short8 qh[4][2], ql[4][2];
    #pragma unroll
    for (int qt = 0; qt < 4; ++qt)
        #pragma unroll
        for (int s = 0; s < 2; ++s) {
            const size_t off = ((size_t)head * SEQ + (size_t)qb * 64 + qt * 16 + lx) * HDIM
                             + s * 32 + q4 * 8;
            qh[qt][s] = *(const short8*)(QHg + off);
            ql[qt][s] = *(const short8*)(QLg + off);
        }

    f32x4 o_acc[4][4];   // [dt][qt]: O^T[d=dt*16+q4*4+r][q=qt*16+lx] (wave-partial)
    float l_part[4] = {0.f, 0.f, 0.f, 0.f};
    #pragma unroll
    for (int dt = 0; dt < 4; ++dt)
        #pragma unroll
        for (int qt = 0; qt < 4; ++qt)
            o_acc[dt][qt] = (f32x4){0.f, 0.f, 0.f, 0.f};

    for (int mt = 0; mt < SEQ / 128; ++mt) {
        const int kbase = mt * 128;
        // ---- stage K hi [128 keys][64 d] and V^T [64 d][128 keys] ----
        ushort8 bk[4], bv[4];
        #pragma unroll
        for (int it = 0; it < 4; ++it) {
            const int idx = it * 256 + t;            // 0..1023
            const int r  = idx >> 3, c8 = (idx & 7) << 3;
            bk[it] = *(const ushort8*)(Kh + (size_t)(kbase + r) * HDIM + c8);
            const int rv = idx >> 4, cv = (idx & 15) << 3;
            bv[it] = *(const ushort8*)(Vg + (size_t)rv * SEQ + kbase + cv);
        }
        #pragma unroll
        for (int it = 0; it < 4; ++it) {
            const int idx = it * 256 + t;
            const int r  = idx >> 3, c8 = (idx & 7) << 3;
            *(ushort8*)&KHI[r * 68 + c8] = bk[it];
            const int rv = idx >> 4, cv = (idx & 15) << 3;
            *(ushort8*)&VS[rv * 136 + cv] = bv[it];
        }
        __syncthreads();

        // ---- S^T = K Q^T per sub-tile; exp packs straight into PV B-frags ----
        short8 phi[4];
        #pragma unroll
        for (int st = 0; st < 2; ++st) {
            const int kr = st * 64 + wv * 16 + lx;   // this lane's A-row (key)
            short8 kfh[2];
            #pragma unroll
            for (int s = 0; s < 2; ++s)
                kfh[s] = *(const short8*)&KHI[kr * 68 + s * 32 + q4 * 8];
            #pragma unroll
            for (int qt = 0; qt < 4; ++qt) {
                f32x4 sa = (f32x4){0.f, 0.f, 0.f, 0.f};
                #pragma unroll
                for (int s = 0; s < 2; ++s) {
                    sa = MFMA_F16(kfh[s], qh[qt][s], sa);
                    sa = MFMA_F16(kfh[s], ql[qt][s], sa);
                }
                #pragma unroll
                for (int r = 0; r < 4; ++r) {
                    const float e = __expf(sa[r]);
                    l_part[qt] += e;
                    phi[qt][st * 4 + r] = (short)f2hu(e);
                }
            }
        }

        // ---- O^T += V^T P^T (A=V^T two b64 reads w/ matching permutation) ----
        #pragma unroll
        for (int dt = 0; dt < 4; ++dt) {
            const int vrow = (dt * 16 + lx) * 136 + wv * 16 + q4 * 4;
            const s16x4 v0 = *(const s16x4*)&VS[vrow];
            const s16x4 v1 = *(const s16x4*)&VS[vrow + 64];
            short8 vf;
            #pragma unroll
            for (int i = 0; i < 4; ++i) { vf[i] = v0[i]; vf[i + 4] = v1[i]; }
            #pragma unroll
            for (int qt = 0; qt < 4; ++qt)
                o_acc[dt][qt] = MFMA_F16(vf, phi[qt], o_acc[dt][qt]);
        }
        __syncthreads();   // staging buffers reused next mega-tile
    }

    // ---- epilogue: reduce l and O^T across the 4 waves, write split out ----
    float lw[4];
    #pragma unroll
    for (int qt = 0; qt < 4; ++qt) {
        float l = l_part[qt];
        l += __shfl_xor(l, 16);
        l += __shfl_xor(l, 32);
        lw[qt] = l;                                  // wave-total for q=qt*16+lx
    }
    if (q4 == 0) {
        #pragma unroll
        for (int qt = 0; qt < 4; ++qt)
            lbuf[wv * 64 + qt * 16 + lx] = lw[qt];
    }
    #pragma unroll
    for (int p = 0; p < 2; ++p) {
        #pragma unroll
        for (int dd = 0; dd < 2; ++dd) {
            const int dt = p * 2 + dd;
            #pragma unroll
            for (int qt = 0; qt < 4; ++qt)
                #pragma unroll
                for (int r = 0; r < 4; ++r)
                    obuf[wv * 2176 + (dd * 16 + q4 * 4 + r) * 68 + qt * 16 + lx]
                        = o_acc[dt][qt][r];
        }
        __syncthreads();
        {
            const int q  = t >> 2;
            const int dg = (t & 3) << 3;
            const float linv = 1.f / (lbuf[q] + lbuf[64 + q] + lbuf[128 + q] + lbuf[192 + q]);
            ushort8 ho, lo;
            #pragma unroll
            for (int j = 0; j < 8; ++j) {
                const int dloc = dg + j;
                const float s = obuf[dloc * 68 + q] + obuf[2176 + dloc * 68 + q]
                              + obuf[4352 + dloc * 68 + q] + obuf[6528 + dloc * 68 + q];
                const float v = s * linv;
                const unsigned short h = f2hu(v);
                ho[j] = (short)h;
                lo[j] = (short)f2hu(v - hu2f(h));
            }
            const size_t ob = (size_t)(qb * 64 + q) * DIMSZ + head * HDIM + p * 32 + dg;
            *(ushort8*)(AttnH + ob) = ho;
            *(ushort8*)(AttnL + ob) = lo;
        }
        __syncthreads();
    }
}

// ---------------------------------------------------------------------------
extern "C" void kernel_launch(void* const* d_in, const int* in_sizes, int n_in,
                              void* d_out, int out_size, void* d_ws,
                              size_t ws_size, hipStream_t stream)
{
    const float* x     = (const float*)d_in[0];   // [4096, 3072]
    const float* Wqkv  = (const float*)d_in[1];   // [3072, 3072]
    const float* Wproj = (const float*)d_in[2];   // [1024, 1024]
    const float* bproj = (const float*)d_in[3];   // [1024]
    float* out = (float*)d_out;

    const size_t NWQ = (size_t)3072 * 3072;       // 9437184
    const size_t NWP = (size_t)1024 * 1024;       // 1048576
    const size_t NX  = (size_t)4096 * 3072;       // 12582912

    unsigned short* ub = (unsigned short*)d_ws;
    unsigned short* AttnH = ub;                   // [4096][1024]
    unsigned short* AttnL = ub + QSZ;
    unsigned short* QHg = ub + 2 * QSZ;           // [16][4096][64]
    unsigned short* QLg = ub + 3 * QSZ;
    unsigned short* KHg = ub + 4 * QSZ;
    unsigned short* VTg = ub + 5 * QSZ;           // [16][64][4096]
    unsigned short* WQH = ub + 6 * QSZ;           // [3072][3072] hi
    unsigned short* WPH = WQH + NWQ;              // [1024][1024] hi
    unsigned short* XH  = WPH + NWP;              // [4096][3072] hi
    unsigned short* XL  = XH + NX;                // [4096][3072] lo
    // base need: (6*QSZ + NWQ + NWP)*2 = 71.3 MB (proven available: R6 ran the
    // 96MiB-gated path). x planes need total 121,634,816 B.
    const bool xsplit = ws_size >= 121634816ull;

    // 0) prep: split x (hi/lo) if room; cast W_qkv/W_proj to fp16 hi.
    prep_split<<<2048, 256, 0, stream>>>(
        xsplit ? x : nullptr, XH, XL, xsplit ? (int)NX : 0,
        Wqkv, WQH, (int)NWQ, Wproj, WPH, (int)NWP);

    // 1) qkv = x @ Wqkv^T (fp16 2-term) -> pre-converted attention operands
    dim3 g1(3 * DIMSZ / 128, SEQ / 128);   // 24 x 32
    if (xsplit)
        mfma_gemm_abt<1, true><<<g1, 256, 0, stream>>>(
            nullptr, XH, XL, WQH, nullptr, nullptr,
            QHg, QLg, KHg, VTg, SEQ, 3 * DIMSZ, 3 * DIMSZ);
    else
        mfma_gemm_abt<1, false><<<g1, 256, 0, stream>>>(
            x, nullptr, nullptr, WQH, nullptr, nullptr,
            QHg, QLg, KHg, VTg, SEQ, 3 * DIMSZ, 3 * DIMSZ);

    // 2) attention (S^T keys-per-wave, register P transit), split fp16 output
    dim3 g2(SEQ / 64, NHEADS);             // 64 x 16
    attn_mfma<<<g2, 256, 0, stream>>>(QHg, QLg, KHg, VTg, AttnH, AttnL);

    // 3) out = attn @ Wproj^T + bproj (fp16 2-term)
    dim3 g3(DIMSZ / 128, SEQ / 128);       // 8 x 32
    mfma_gemm_abt<0, true><<<g3, 256, 0, stream>>>(
        nullptr, AttnH, AttnL, WPH, bproj, out,
        nullptr, nullptr, nullptr, nullptr, SEQ, DIMSZ, DIMSZ);
}